// Round 3
// baseline (2761.202 us; speedup 1.0000x reference)
//
#include <hip/hip_runtime.h>

// Problem sizes (fixed)
#define BB 512
#define TT 256
#define II 256
#define HH 512
// K = II + HH = 768 ; 4H = 2048

typedef __attribute__((ext_vector_type(8))) short bf16x8;   // 4 VGPRs (8 bf16)
typedef __attribute__((ext_vector_type(4))) float f32x4;    // 16x16 accumulator

__device__ __forceinline__ unsigned short f2bf(float f) {
  union { float f; unsigned u; } v; v.f = f;
  unsigned r = v.u + 0x7fffu + ((v.u >> 16) & 1u);   // RNE
  return (unsigned short)(r >> 16);
}

// -------- workspace layout (bytes) --------
// [0,4096)                : group barrier counters (one per 512B)
// [4096, 4096+2*524288)   : hswz double buffer (h in A-frag swizzle, zeroed)
// [OFF_XSWZ, +64MB)       : x in A-frag swizzle (bf16); later reused for 'a' (fp32, 16MB)
// [OFF_HIST, +128MB)      : lstm_out history (bf16, [B*T][H])
#define OFF_CNT   0
#define OFF_HSWZ  4096
#define OFF_XSWZ  1052672ULL
#define OFF_HIST  68161536ULL
#define ZERO_WORDS 263168   // (4096 + 2*524288)/4

__global__ void zero_k(unsigned* __restrict__ p, int n) {
  int i = blockIdx.x * blockDim.x + threadIdx.x;
  if (i < n) p[i] = 0u;
}

// Swizzle x[b][t][k] (fp32) -> xswz[t][kc][rc][lane][8] (bf16), A-frag order.
// Coalesced: block = (t, rc) tile; row reads contiguous; LDS transpose.
__global__ __launch_bounds__(256) void prep_x(const float* __restrict__ x,
                                              unsigned char* __restrict__ ws) {
  __shared__ unsigned short xs[16][264];   // 16 rows x 256 k (+8 pad)
  const int t = blockIdx.x >> 5, rc = blockIdx.x & 31;
  const int tid = threadIdx.x;
  {
    const int r = tid >> 4, seg = tid & 15;
    const float* src = x + ((size_t)(rc * 16 + r) * TT + t) * II + seg * 16;
    const float4* s4 = (const float4*)src;
#pragma unroll
    for (int q = 0; q < 4; ++q) {
      float4 v = s4[q];
      xs[r][seg * 16 + q * 4 + 0] = f2bf(v.x);
      xs[r][seg * 16 + q * 4 + 1] = f2bf(v.y);
      xs[r][seg * 16 + q * 4 + 2] = f2bf(v.z);
      xs[r][seg * 16 + q * 4 + 3] = f2bf(v.w);
    }
  }
  __syncthreads();
  const int lane = tid & 63;
  const int row16 = lane & 15, koff = (lane >> 4) * 8;
#pragma unroll
  for (int kc = tid >> 6; kc < 8; kc += 4) {
    union { unsigned short h[8]; uint4 v; } pk;
#pragma unroll
    for (int j = 0; j < 8; ++j) pk.h[j] = xs[row16][kc * 32 + koff + j];
    *(uint4*)(ws + OFF_XSWZ + (size_t)(t * 8 + kc) * 32768u +
              ((size_t)rc * 64 + lane) * 16) = pk.v;
  }
}

// Persistent fused LSTM. 256 blocks x 256 threads, 1 block/CU.
// group = blockIdx&7 (XCD-affine), member m = blockIdx>>3.
// Group owns batch rows [group*64,+64); member owns h-cols [m*16,+16)
// (gate cols nt*512 + m*16 + [0,16), nt = i,f,g,o).
// NEW: each wave owns one 16-row chunk with FULL K=768 -> all 4 gates of a
// cell land in one thread's accs (C/D: col=ln, row=lq*4+r) -> cell state in
// registers, no split-K LDS reduce. x-part MFMAs issue BEFORE the barrier
// wait (no h dependence) to overlap member skew + detect latency.
__global__ __launch_bounds__(256, 1) void lstm_persist(
    const float* __restrict__ Wih, const float* __restrict__ Whh,
    const float* __restrict__ bih, const float* __restrict__ bhh,
    unsigned char* __restrict__ ws)
{
  const int gid = blockIdx.x;
  const int group = gid & 7;
  const int m = gid >> 3;
  const int tid = threadIdx.x;
  const int wv = tid >> 6, lane = tid & 63;
  const int lq = lane >> 4, ln = lane & 15;  // quad, low nibble

  int* cnt = (int*)(ws + OFF_CNT + (size_t)group * 512);
  unsigned char* xswz  = ws + OFF_XSWZ;
  unsigned char* hswz0 = ws + OFF_HSWZ;
  unsigned char* hswz1 = ws + OFF_HSWZ + 524288;
  unsigned char* hist  = ws + OFF_HIST;

  // ---- W preload: full K per wave, Wf[kk][nt]; 384 VGPRs ----
  bf16x8 Wf[24][4];
#pragma unroll
  for (int kk = 0; kk < 24; ++kk) {
    const int kb = kk * 32 + lq * 8;   // 0..760, never straddles 256
#pragma unroll
    for (int nt = 0; nt < 4; ++nt) {
      const int gcol = nt * 512 + m * 16 + ln;
      const float* s = (kb < 256) ? (Wih + (size_t)gcol * 256 + kb)
                                  : (Whh + (size_t)gcol * 512 + (kb - 256));
      bf16x8 w;
#pragma unroll
      for (int j = 0; j < 8; ++j) w[j] = (short)f2bf(s[j]);
      Wf[kk][nt] = w;
    }
  }

  // per-thread bias (4 gates at col ln)
  float bia[4];
#pragma unroll
  for (int nt = 0; nt < 4; ++nt) {
    int gcol = nt * 512 + m * 16 + ln;
    bia[nt] = bih[gcol] + bhh[gcol];
  }

  __shared__ float h_s[64 * 17];   // new h staging (fp32)

  const int rc = group * 4 + wv;     // this wave's 16-row chunk
  float creg[4] = {0.f, 0.f, 0.f, 0.f};   // cell state, rows lq*4+r, col ln
  const f32x4 zero4 = {0.f, 0.f, 0.f, 0.f};

#pragma unroll 1
  for (int t = 0; t < 256; ++t) {
    unsigned char* hrd = (t & 1) ? hswz1 : hswz0;
    unsigned char* hwr = (t & 1) ? hswz0 : hswz1;

    f32x4 acc[4] = {zero4, zero4, zero4, zero4};

    // ---- x-part (k = 0..256): no h dependence, runs during member skew ----
#pragma unroll
    for (int kk = 0; kk < 8; ++kk) {
      bf16x8 a = *(const bf16x8*)(xswz + (size_t)(t * 8 + kk) * 32768u +
                                  ((size_t)rc * 64 + lane) * 16);
#pragma unroll
      for (int nt = 0; nt < 4; ++nt)
        acc[nt] = __builtin_amdgcn_mfma_f32_16x16x32_bf16(a, Wf[kk][nt], acc[nt], 0, 0, 0);
    }

    // ---- wait: all 32 members published h for step t-1 ----
    if (t > 0 && tid == 0) {
      int iter = 0;
      while (__hip_atomic_load(cnt, __ATOMIC_RELAXED, __HIP_MEMORY_SCOPE_AGENT) < t * 32
             && iter < (1 << 18)) { ++iter; __builtin_amdgcn_s_sleep(1); }
    }
    __syncthreads();

    // ---- h-part (k = 256..768): coherent cache-bypass 8B loads ----
#pragma unroll
    for (int kk = 0; kk < 16; ++kk) {
      const unsigned long long* p =
          (const unsigned long long*)(hrd + (size_t)kk * 32768u +
                                      ((size_t)rc * 64 + lane) * 16);
      union { unsigned long long q[2]; bf16x8 v; } u;
      u.q[0] = __hip_atomic_load(p + 0, __ATOMIC_RELAXED, __HIP_MEMORY_SCOPE_AGENT);
      u.q[1] = __hip_atomic_load(p + 1, __ATOMIC_RELAXED, __HIP_MEMORY_SCOPE_AGENT);
#pragma unroll
      for (int nt = 0; nt < 4; ++nt)
        acc[nt] = __builtin_amdgcn_mfma_f32_16x16x32_bf16(u.v, Wf[8 + kk][nt], acc[nt], 0, 0, 0);
    }

    // ---- cell update fully in registers (4 cells/thread) ----
#pragma unroll
    for (int r = 0; r < 4; ++r) {
      float gi = acc[0][r] + bia[0];
      float gf = acc[1][r] + bia[1];
      float gg = acc[2][r] + bia[2];
      float go = acc[3][r] + bia[3];
      float iv = 1.f / (1.f + __expf(-gi));
      float fv = 1.f / (1.f + __expf(-gf));
      float gv = 1.f - 2.f / (__expf(2.f * gg) + 1.f);
      float ov = 1.f / (1.f + __expf(-go));
      float cv = fv * creg[r] + iv * gv;
      creg[r] = cv;
      float h = ov * (1.f - 2.f / (__expf(2.f * cv) + 1.f));
      h_s[(wv * 16 + lq * 4 + r) * 17 + ln] = h;
    }
    __syncthreads();

    // ---- publish h into hwr in A-frag swizzle (8B coherent store/thread) ----
    {
      int rc_l = tid >> 6;                // 0..3 (row chunk)
      int rem = tid & 63;
      int lane_off = rem >> 1;            // 0..31
      int half = rem & 1;
      int l2 = (m & 1) * 32 + lane_off;   // target lane in chunk
      int rowl = rc_l * 16 + (lane_off & 15);
      int jb = (lane_off >> 4) * 8 + half * 4;
      union { ushort4 s; unsigned long long q; } pk;
      pk.s = make_ushort4(f2bf(h_s[rowl * 17 + jb + 0]),
                          f2bf(h_s[rowl * 17 + jb + 1]),
                          f2bf(h_s[rowl * 17 + jb + 2]),
                          f2bf(h_s[rowl * 17 + jb + 3]));
      size_t off = ((size_t)((m >> 1) * 32 + group * 4 + rc_l) * 64 + l2) * 16 + half * 8;
      __hip_atomic_store((unsigned long long*)(hwr + off), pk.q,
                         __ATOMIC_RELAXED, __HIP_MEMORY_SCOPE_AGENT);
    }
    // ---- hist store (plain, via L2) ----
    {
      int row = tid >> 2, jb = (tid & 3) * 4;
      ushort4 hq = make_ushort4(f2bf(h_s[row * 17 + jb + 0]),
                                f2bf(h_s[row * 17 + jb + 1]),
                                f2bf(h_s[row * 17 + jb + 2]),
                                f2bf(h_s[row * 17 + jb + 3]));
      int b = group * 64 + row;
      *(ushort4*)(hist + ((size_t)(b * 256 + t) * 512 + m * 16 + jb) * 2) = hq;
    }
    __syncthreads();   // drains vmcnt(0): publishes at coherence point

    if (tid == 0)
      __hip_atomic_fetch_add(cnt, 1, __ATOMIC_RELAXED, __HIP_MEMORY_SCOPE_AGENT);
  }
}

// Epilogue 1: a[r][0..32) = lstm_hist[r][:] @ fc1_w^T   (r = b*T + t), fp32 out, no bias.
__global__ __launch_bounds__(256) void e1_fc1(
    const float* __restrict__ fc1_w, const unsigned char* __restrict__ hist,
    float* __restrict__ a_out)
{
  const int tid = threadIdx.x, wv = tid >> 6, lane = tid & 63;
  const int lq = lane >> 4, ln = lane & 15;

  bf16x8 Bf[16][2];
#pragma unroll
  for (int kk = 0; kk < 16; ++kk) {
#pragma unroll
    for (int nt = 0; nt < 2; ++nt) {
      const float* s = fc1_w + (size_t)(nt * 16 + ln) * 512 + kk * 32 + lq * 8;
      bf16x8 w;
#pragma unroll
      for (int j = 0; j < 8; ++j) w[j] = (short)f2bf(s[j]);
      Bf[kk][nt] = w;
    }
  }

  const int rbase = blockIdx.x * 128 + wv * 32;
  const f32x4 zero4 = {0.f, 0.f, 0.f, 0.f};
  f32x4 acc[2][2] = {{zero4, zero4}, {zero4, zero4}};
#pragma unroll
  for (int kk = 0; kk < 16; ++kk) {
    bf16x8 a0 = *(const bf16x8*)(hist + ((size_t)(rbase + ln) * 512 + kk * 32 + lq * 8) * 2);
    bf16x8 a1 = *(const bf16x8*)(hist + ((size_t)(rbase + 16 + ln) * 512 + kk * 32 + lq * 8) * 2);
#pragma unroll
    for (int nt = 0; nt < 2; ++nt) {
      acc[0][nt] = __builtin_amdgcn_mfma_f32_16x16x32_bf16(a0, Bf[kk][nt], acc[0][nt], 0, 0, 0);
      acc[1][nt] = __builtin_amdgcn_mfma_f32_16x16x32_bf16(a1, Bf[kk][nt], acc[1][nt], 0, 0, 0);
    }
  }
#pragma unroll
  for (int mt = 0; mt < 2; ++mt)
#pragma unroll
    for (int nt = 0; nt < 2; ++nt)
#pragma unroll
      for (int r = 0; r < 4; ++r) {
        int row = rbase + mt * 16 + lq * 4 + r;
        a_out[(size_t)row * 32 + nt * 16 + ln] = acc[mt][nt][r];
      }
}

// Epilogue 2: per-t BN1 + leaky-relu + fc2 + BN2 + relu. One block per t.
__global__ __launch_bounds__(256) void e2_head(
    const float* __restrict__ a_in, const float* __restrict__ fc1_b,
    const float* __restrict__ fc2_w, const float* __restrict__ fc2_b,
    const float* __restrict__ bn1_g, const float* __restrict__ bn1_b,
    const float* __restrict__ bn2_g, const float* __restrict__ bn2_b,
    float* __restrict__ out)
{
  const int t = blockIdx.x, tid = threadIdx.x;
  __shared__ float fb[32], fw[32];
  __shared__ float red[4][2], red2[4][2];
  if (tid < 32) { fb[tid] = fc1_b[tid]; fw[tid] = fc2_w[tid]; }
  __syncthreads();

  float va[2][32];
  float s1 = 0.f, s2 = 0.f;
#pragma unroll
  for (int rr = 0; rr < 2; ++rr) {
    int b = tid * 2 + rr;
    const float* p = a_in + ((size_t)b * 256 + t) * 32;
#pragma unroll
    for (int o = 0; o < 32; ++o) {
      float v = p[o] + fb[o];
      va[rr][o] = v;
      s1 += v; s2 += v * v;
    }
  }
#pragma unroll
  for (int off = 32; off > 0; off >>= 1) {
    s1 += __shfl_down(s1, off);
    s2 += __shfl_down(s2, off);
  }
  if ((tid & 63) == 0) { red[tid >> 6][0] = s1; red[tid >> 6][1] = s2; }
  __syncthreads();
  float tot1 = red[0][0] + red[1][0] + red[2][0] + red[3][0];
  float tot2 = red[0][1] + red[1][1] + red[2][1] + red[3][1];
  float m1 = tot1 * (1.f / 16384.f);
  float v1 = tot2 * (1.f / 16384.f) - m1 * m1;
  float sc1 = bn1_g[t] * rsqrtf(v1 + 1e-5f);
  float sh1 = bn1_b[t];

  float z[2];
  float zs1 = 0.f, zs2 = 0.f;
#pragma unroll
  for (int rr = 0; rr < 2; ++rr) {
    float acc = fc2_b[0];
#pragma unroll
    for (int o = 0; o < 32; ++o) {
      float av = (va[rr][o] - m1) * sc1 + sh1;
      av = (av > 0.f) ? av : 0.1f * av;
      acc += av * fw[o];
    }
    z[rr] = acc; zs1 += acc; zs2 += acc * acc;
  }
#pragma unroll
  for (int off = 32; off > 0; off >>= 1) {
    zs1 += __shfl_down(zs1, off);
    zs2 += __shfl_down(zs2, off);
  }
  if ((tid & 63) == 0) { red2[tid >> 6][0] = zs1; red2[tid >> 6][1] = zs2; }
  __syncthreads();
  float zt1 = red2[0][0] + red2[1][0] + red2[2][0] + red2[3][0];
  float zt2 = red2[0][1] + red2[1][1] + red2[2][1] + red2[3][1];
  float m2 = zt1 * (1.f / 512.f);
  float v2 = zt2 * (1.f / 512.f) - m2 * m2;
  float sc2 = bn2_g[t] * rsqrtf(v2 + 1e-5f);
  float sh2 = bn2_b[t];
#pragma unroll
  for (int rr = 0; rr < 2; ++rr) {
    int b = tid * 2 + rr;
    float res = (z[rr] - m2) * sc2 + sh2;
    out[(size_t)b * 256 + t] = (res > 0.f) ? res : 0.f;
  }
}

extern "C" void kernel_launch(void* const* d_in, const int* in_sizes, int n_in,
                              void* d_out, int out_size, void* d_ws, size_t ws_size,
                              hipStream_t stream) {
  const float* x    = (const float*)d_in[0];
  const float* Wih  = (const float*)d_in[1];
  const float* Whh  = (const float*)d_in[2];
  const float* bih  = (const float*)d_in[3];
  const float* bhh  = (const float*)d_in[4];
  const float* fc1w = (const float*)d_in[5];
  const float* fc1b = (const float*)d_in[6];
  const float* fc2w = (const float*)d_in[7];
  const float* fc2b = (const float*)d_in[8];
  const float* b1g  = (const float*)d_in[9];
  const float* b1b  = (const float*)d_in[10];
  const float* b2g  = (const float*)d_in[11];
  const float* b2b  = (const float*)d_in[12];
  unsigned char* ws = (unsigned char*)d_ws;
  float* out = (float*)d_out;
  float* a_buf = (float*)(ws + OFF_XSWZ);   // reuses xswz region after persist

  zero_k<<<1028, 256, 0, stream>>>((unsigned*)ws, ZERO_WORDS);
  prep_x<<<8192, 256, 0, stream>>>(x, ws);
  lstm_persist<<<256, 256, 0, stream>>>(Wih, Whh, bih, bhh, ws);
  e1_fc1<<<1024, 256, 0, stream>>>(fc1w, ws + OFF_HIST, a_buf);
  e2_head<<<256, 256, 0, stream>>>(a_buf, fc1b, fc2w, fc2b, b1g, b1b, b2g, b2b, out);
}

// Round 4
// 1661.376 us; speedup vs baseline: 1.6620x; 1.6620x over previous
//
#include <hip/hip_runtime.h>

// Problem sizes (fixed)
#define BB 512
#define TT 256
#define II 256
#define HH 512
// K = II + HH = 768 ; 4H = 2048

typedef __attribute__((ext_vector_type(8))) short bf16x8;   // 4 VGPRs (8 bf16)
typedef __attribute__((ext_vector_type(4))) float f32x4;    // 16x16 accumulator

__device__ __forceinline__ unsigned short f2bf(float f) {
  union { float f; unsigned u; } v; v.f = f;
  unsigned r = v.u + 0x7fffu + ((v.u >> 16) & 1u);   // RNE
  return (unsigned short)(r >> 16);
}

// -------- workspace layout (bytes) --------
// [0,4096)                : group barrier counters (one per 512B)
// [4096, 4096+2*524288)   : hswz double buffer (h in A-frag swizzle, zeroed)
// [OFF_XSWZ, +64MB)       : x in A-frag swizzle (bf16); later reused for 'a' (fp32, 16MB)
// [OFF_HIST, +128MB)      : lstm_out history (bf16, [B*T][H])
#define OFF_CNT   0
#define OFF_HSWZ  4096
#define OFF_XSWZ  1052672ULL
#define OFF_HIST  68161536ULL
#define ZERO_WORDS 263168   // (4096 + 2*524288)/4

__global__ void zero_k(unsigned* __restrict__ p, int n) {
  int i = blockIdx.x * blockDim.x + threadIdx.x;
  if (i < n) p[i] = 0u;
}

// Swizzle x[b][t][k] (fp32) -> xswz[t][kc][rc][lane][8] (bf16), A-frag order.
// Coalesced: block = (t, rc) tile; row reads contiguous; LDS transpose.
__global__ __launch_bounds__(256) void prep_x(const float* __restrict__ x,
                                              unsigned char* __restrict__ ws) {
  __shared__ unsigned short xs[16][264];   // 16 rows x 256 k (+8 pad)
  const int t = blockIdx.x >> 5, rc = blockIdx.x & 31;
  const int tid = threadIdx.x;
  {
    const int r = tid >> 4, seg = tid & 15;
    const float* src = x + ((size_t)(rc * 16 + r) * TT + t) * II + seg * 16;
    const float4* s4 = (const float4*)src;
#pragma unroll
    for (int q = 0; q < 4; ++q) {
      float4 v = s4[q];
      xs[r][seg * 16 + q * 4 + 0] = f2bf(v.x);
      xs[r][seg * 16 + q * 4 + 1] = f2bf(v.y);
      xs[r][seg * 16 + q * 4 + 2] = f2bf(v.z);
      xs[r][seg * 16 + q * 4 + 3] = f2bf(v.w);
    }
  }
  __syncthreads();
  const int lane = tid & 63;
  const int row16 = lane & 15, koff = (lane >> 4) * 8;
#pragma unroll
  for (int kc = tid >> 6; kc < 8; kc += 4) {
    union { unsigned short h[8]; uint4 v; } pk;
#pragma unroll
    for (int j = 0; j < 8; ++j) pk.h[j] = xs[row16][kc * 32 + koff + j];
    *(uint4*)(ws + OFF_XSWZ + (size_t)(t * 8 + kc) * 32768u +
              ((size_t)rc * 64 + lane) * 16) = pk.v;
  }
}

// Persistent fused LSTM. 256 blocks x 512 threads (8 waves, 2/SIMD), 1 block/CU.
// group = blockIdx&7 (XCD-affine), member m = blockIdx>>3.
// Group owns batch rows [group*64,+64); member owns h-cols [m*16,+16)
// (gate cols nt*512 + m*16 + [0,16), nt = i,f,g,o).
// Wave wv: mb = wv&3 -> m-tile rows [mb*16,+16); kh = wv>>2 -> K-half.
//   kh=0: k-chunks 0..11 (x 0..7 + h 0..3); kh=1: k-chunks 12..23 (h 4..15).
// W slice per wave = 12x(4x16 cols) = 192 VGPRs (R2's proven no-spill budget).
// Split-K folded into cell update: kh=1 writes partials to LDS once; kh=0 adds
// in-register and keeps cell state in registers (4 cells/thread, 4 gates in acc).
// x-part MFMAs issue before the poll; h-loads software-pipelined (depth 6);
// per-wave polling (no sync around it); 3 barriers/step.
__global__ __launch_bounds__(512, 2) void lstm_persist(
    const float* __restrict__ Wih, const float* __restrict__ Whh,
    const float* __restrict__ bih, const float* __restrict__ bhh,
    unsigned char* __restrict__ ws)
{
  const int gid = blockIdx.x;
  const int group = gid & 7;
  const int m = gid >> 3;
  const int tid = threadIdx.x;
  const int wv = tid >> 6, lane = tid & 63;
  const int mb = wv & 3, kh = wv >> 2;       // m-tile, K-half
  const int lq = lane >> 4, ln = lane & 15;  // quad, low nibble

  int* cnt = (int*)(ws + OFF_CNT + (size_t)group * 512);
  unsigned char* xswz  = ws + OFF_XSWZ;
  unsigned char* hswz0 = ws + OFF_HSWZ;
  unsigned char* hswz1 = ws + OFF_HSWZ + 524288;
  unsigned char* hist  = ws + OFF_HIST;

  // ---- W preload: kw = kh*12+kk ; Wf[kk][nt] = 192 VGPRs ----
  bf16x8 Wf[12][4];
#pragma unroll
  for (int kk = 0; kk < 12; ++kk) {
    const int kb = (kh * 12 + kk) * 32 + lq * 8;   // never straddles 256
#pragma unroll
    for (int nt = 0; nt < 4; ++nt) {
      const int gcol = nt * 512 + m * 16 + ln;
      const float* s = (kb < 256) ? (Wih + (size_t)gcol * 256 + kb)
                                  : (Whh + (size_t)gcol * 512 + (kb - 256));
      bf16x8 w;
#pragma unroll
      for (int j = 0; j < 8; ++j) w[j] = (short)f2bf(s[j]);
      Wf[kk][nt] = w;
    }
  }

  float bia[4];
#pragma unroll
  for (int nt = 0; nt < 4; ++nt) {
    int gcol = nt * 512 + m * 16 + ln;
    bia[nt] = bih[gcol] + bhh[gcol];
  }

  __shared__ float g_s[64 * 68];   // kh=1 partial gate preacts [row][gate*16+ln]
  __shared__ float h_s[64 * 17];   // new h staging (fp32)

  const size_t aoff = ((size_t)(group * 4 + mb) * 64 + lane) * 16;  // A-frag offset
  float creg[4] = {0.f, 0.f, 0.f, 0.f};   // cell state (kh=0): rows lq*4+r, col ln
  const f32x4 zero4 = {0.f, 0.f, 0.f, 0.f};

#pragma unroll 1
  for (int t = 0; t < 256; ++t) {
    unsigned char* hrd = (t & 1) ? hswz1 : hswz0;
    unsigned char* hwr = (t & 1) ? hswz0 : hswz1;

    f32x4 acc[4] = {zero4, zero4, zero4, zero4};

    // ---- x-part (kh=0 only, k-chunks 0..7): before the poll ----
    if (kh == 0) {
#pragma unroll
      for (int kk = 0; kk < 8; ++kk) {
        bf16x8 a = *(const bf16x8*)(xswz + (size_t)(t * 8 + kk) * 32768u + aoff);
#pragma unroll
        for (int nt = 0; nt < 4; ++nt)
          acc[nt] = __builtin_amdgcn_mfma_f32_16x16x32_bf16(a, Wf[kk][nt], acc[nt], 0, 0, 0);
      }
    }

    // ---- per-wave poll: all 32 member-blocks published step t-1 ----
    if (t > 0) {
      int iter = 0;
      while (__hip_atomic_load(cnt, __ATOMIC_RELAXED, __HIP_MEMORY_SCOPE_AGENT) < t * 32
             && iter < (1 << 17)) { ++iter; __builtin_amdgcn_s_sleep(1); }
    }

    // ---- h-part: coherent cache-bypass 8B loads, software-pipelined ----
    if (kh == 0) {
      // h-chunks 0..3 with Wf[8..11]: batch all loads, then consume
      unsigned long long u0[4], u1[4];
#pragma unroll
      for (int p = 0; p < 4; ++p) {
        const unsigned long long* q =
            (const unsigned long long*)(hrd + (size_t)p * 32768u + aoff);
        u0[p] = __hip_atomic_load(q + 0, __ATOMIC_RELAXED, __HIP_MEMORY_SCOPE_AGENT);
        u1[p] = __hip_atomic_load(q + 1, __ATOMIC_RELAXED, __HIP_MEMORY_SCOPE_AGENT);
      }
#pragma unroll
      for (int kk = 0; kk < 4; ++kk) {
        union { unsigned long long q[2]; bf16x8 v; } u;
        u.q[0] = u0[kk]; u.q[1] = u1[kk];
#pragma unroll
        for (int nt = 0; nt < 4; ++nt)
          acc[nt] = __builtin_amdgcn_mfma_f32_16x16x32_bf16(u.v, Wf[8 + kk][nt], acc[nt], 0, 0, 0);
      }
    } else {
      // h-chunks 4..15 with Wf[0..11]: rotating prefetch, depth 6
      unsigned long long u0[6], u1[6];
#pragma unroll
      for (int p = 0; p < 6; ++p) {
        const unsigned long long* q =
            (const unsigned long long*)(hrd + (size_t)(4 + p) * 32768u + aoff);
        u0[p] = __hip_atomic_load(q + 0, __ATOMIC_RELAXED, __HIP_MEMORY_SCOPE_AGENT);
        u1[p] = __hip_atomic_load(q + 1, __ATOMIC_RELAXED, __HIP_MEMORY_SCOPE_AGENT);
      }
#pragma unroll
      for (int kk = 0; kk < 12; ++kk) {
        const int slot = kk % 6;
        union { unsigned long long q[2]; bf16x8 v; } u;
        u.q[0] = u0[slot]; u.q[1] = u1[slot];
        if (kk < 6) {
          const unsigned long long* q =
              (const unsigned long long*)(hrd + (size_t)(10 + kk) * 32768u + aoff);
          u0[slot] = __hip_atomic_load(q + 0, __ATOMIC_RELAXED, __HIP_MEMORY_SCOPE_AGENT);
          u1[slot] = __hip_atomic_load(q + 1, __ATOMIC_RELAXED, __HIP_MEMORY_SCOPE_AGENT);
        }
#pragma unroll
        for (int nt = 0; nt < 4; ++nt)
          acc[nt] = __builtin_amdgcn_mfma_f32_16x16x32_bf16(u.v, Wf[kk][nt], acc[nt], 0, 0, 0);
      }
      // write partials to LDS (C/D: col=ln, row=lq*4+r)
#pragma unroll
      for (int nt = 0; nt < 4; ++nt)
#pragma unroll
        for (int r = 0; r < 4; ++r)
          g_s[(mb * 16 + lq * 4 + r) * 68 + nt * 16 + ln] = acc[nt][r];
    }
    __syncthreads();   // A: partials visible

    // ---- cell update (kh=0): add partials, 4 cells/thread in registers ----
    if (kh == 0) {
#pragma unroll
      for (int r = 0; r < 4; ++r) {
        const int rw = mb * 16 + lq * 4 + r;
        float gi = acc[0][r] + g_s[rw * 68 + ln]      + bia[0];
        float gf = acc[1][r] + g_s[rw * 68 + 16 + ln] + bia[1];
        float gg = acc[2][r] + g_s[rw * 68 + 32 + ln] + bia[2];
        float go = acc[3][r] + g_s[rw * 68 + 48 + ln] + bia[3];
        float iv = 1.f / (1.f + __expf(-gi));
        float fv = 1.f / (1.f + __expf(-gf));
        float gv = 1.f - 2.f / (__expf(2.f * gg) + 1.f);
        float ov = 1.f / (1.f + __expf(-go));
        float cv = fv * creg[r] + iv * gv;
        creg[r] = cv;
        h_s[rw * 17 + ln] = ov * (1.f - 2.f / (__expf(2.f * cv) + 1.f));
      }
    }
    __syncthreads();   // B: h_s ready

    if (tid < 256) {
      // ---- publish h into hwr in A-frag swizzle (8B coherent store/thread) ----
      {
        int rc_l = tid >> 6;                // 0..3 (row chunk)
        int rem = tid & 63;
        int lane_off = rem >> 1;            // 0..31
        int half = rem & 1;
        int l2 = (m & 1) * 32 + lane_off;   // target lane in chunk
        int rowl = rc_l * 16 + (lane_off & 15);
        int jb = (lane_off >> 4) * 8 + half * 4;
        union { ushort4 s; unsigned long long q; } pk;
        pk.s = make_ushort4(f2bf(h_s[rowl * 17 + jb + 0]),
                            f2bf(h_s[rowl * 17 + jb + 1]),
                            f2bf(h_s[rowl * 17 + jb + 2]),
                            f2bf(h_s[rowl * 17 + jb + 3]));
        size_t off = ((size_t)((m >> 1) * 32 + group * 4 + rc_l) * 64 + l2) * 16 + half * 8;
        __hip_atomic_store((unsigned long long*)(hwr + off), pk.q,
                           __ATOMIC_RELAXED, __HIP_MEMORY_SCOPE_AGENT);
      }
      // ---- hist store (plain, via L2) ----
      {
        int row = tid >> 2, jb = (tid & 3) * 4;
        ushort4 hq = make_ushort4(f2bf(h_s[row * 17 + jb + 0]),
                                  f2bf(h_s[row * 17 + jb + 1]),
                                  f2bf(h_s[row * 17 + jb + 2]),
                                  f2bf(h_s[row * 17 + jb + 3]));
        int b = group * 64 + row;
        *(ushort4*)(hist + ((size_t)(b * 256 + t) * 512 + m * 16 + jb) * 2) = hq;
      }
    }
    __syncthreads();   // C: every wave's vmcnt drained -> publishes at IC

    if (tid == 0)
      __hip_atomic_fetch_add(cnt, 1, __ATOMIC_RELAXED, __HIP_MEMORY_SCOPE_AGENT);
  }
}

// Epilogue 1: a[r][0..32) = lstm_hist[r][:] @ fc1_w^T   (r = b*T + t), fp32 out, no bias.
__global__ __launch_bounds__(256) void e1_fc1(
    const float* __restrict__ fc1_w, const unsigned char* __restrict__ hist,
    float* __restrict__ a_out)
{
  const int tid = threadIdx.x, wv = tid >> 6, lane = tid & 63;
  const int lq = lane >> 4, ln = lane & 15;

  bf16x8 Bf[16][2];
#pragma unroll
  for (int kk = 0; kk < 16; ++kk) {
#pragma unroll
    for (int nt = 0; nt < 2; ++nt) {
      const float* s = fc1_w + (size_t)(nt * 16 + ln) * 512 + kk * 32 + lq * 8;
      bf16x8 w;
#pragma unroll
      for (int j = 0; j < 8; ++j) w[j] = (short)f2bf(s[j]);
      Bf[kk][nt] = w;
    }
  }

  const int rbase = blockIdx.x * 128 + wv * 32;
  const f32x4 zero4 = {0.f, 0.f, 0.f, 0.f};
  f32x4 acc[2][2] = {{zero4, zero4}, {zero4, zero4}};
#pragma unroll
  for (int kk = 0; kk < 16; ++kk) {
    bf16x8 a0 = *(const bf16x8*)(hist + ((size_t)(rbase + ln) * 512 + kk * 32 + lq * 8) * 2);
    bf16x8 a1 = *(const bf16x8*)(hist + ((size_t)(rbase + 16 + ln) * 512 + kk * 32 + lq * 8) * 2);
#pragma unroll
    for (int nt = 0; nt < 2; ++nt) {
      acc[0][nt] = __builtin_amdgcn_mfma_f32_16x16x32_bf16(a0, Bf[kk][nt], acc[0][nt], 0, 0, 0);
      acc[1][nt] = __builtin_amdgcn_mfma_f32_16x16x32_bf16(a1, Bf[kk][nt], acc[1][nt], 0, 0, 0);
    }
  }
#pragma unroll
  for (int mt = 0; mt < 2; ++mt)
#pragma unroll
    for (int nt = 0; nt < 2; ++nt)
#pragma unroll
      for (int r = 0; r < 4; ++r) {
        int row = rbase + mt * 16 + lq * 4 + r;
        a_out[(size_t)row * 32 + nt * 16 + ln] = acc[mt][nt][r];
      }
}

// Epilogue 2: per-t BN1 + leaky-relu + fc2 + BN2 + relu. One block per t.
__global__ __launch_bounds__(256) void e2_head(
    const float* __restrict__ a_in, const float* __restrict__ fc1_b,
    const float* __restrict__ fc2_w, const float* __restrict__ fc2_b,
    const float* __restrict__ bn1_g, const float* __restrict__ bn1_b,
    const float* __restrict__ bn2_g, const float* __restrict__ bn2_b,
    float* __restrict__ out)
{
  const int t = blockIdx.x, tid = threadIdx.x;
  __shared__ float fb[32], fw[32];
  __shared__ float red[4][2], red2[4][2];
  if (tid < 32) { fb[tid] = fc1_b[tid]; fw[tid] = fc2_w[tid]; }
  __syncthreads();

  float va[2][32];
  float s1 = 0.f, s2 = 0.f;
#pragma unroll
  for (int rr = 0; rr < 2; ++rr) {
    int b = tid * 2 + rr;
    const float* p = a_in + ((size_t)b * 256 + t) * 32;
#pragma unroll
    for (int o = 0; o < 32; ++o) {
      float v = p[o] + fb[o];
      va[rr][o] = v;
      s1 += v; s2 += v * v;
    }
  }
#pragma unroll
  for (int off = 32; off > 0; off >>= 1) {
    s1 += __shfl_down(s1, off);
    s2 += __shfl_down(s2, off);
  }
  if ((tid & 63) == 0) { red[tid >> 6][0] = s1; red[tid >> 6][1] = s2; }
  __syncthreads();
  float tot1 = red[0][0] + red[1][0] + red[2][0] + red[3][0];
  float tot2 = red[0][1] + red[1][1] + red[2][1] + red[3][1];
  float m1 = tot1 * (1.f / 16384.f);
  float v1 = tot2 * (1.f / 16384.f) - m1 * m1;
  float sc1 = bn1_g[t] * rsqrtf(v1 + 1e-5f);
  float sh1 = bn1_b[t];

  float z[2];
  float zs1 = 0.f, zs2 = 0.f;
#pragma unroll
  for (int rr = 0; rr < 2; ++rr) {
    float acc = fc2_b[0];
#pragma unroll
    for (int o = 0; o < 32; ++o) {
      float av = (va[rr][o] - m1) * sc1 + sh1;
      av = (av > 0.f) ? av : 0.1f * av;
      acc += av * fw[o];
    }
    z[rr] = acc; zs1 += acc; zs2 += acc * acc;
  }
#pragma unroll
  for (int off = 32; off > 0; off >>= 1) {
    zs1 += __shfl_down(zs1, off);
    zs2 += __shfl_down(zs2, off);
  }
  if ((tid & 63) == 0) { red2[tid >> 6][0] = zs1; red2[tid >> 6][1] = zs2; }
  __syncthreads();
  float zt1 = red2[0][0] + red2[1][0] + red2[2][0] + red2[3][0];
  float zt2 = red2[0][1] + red2[1][1] + red2[2][1] + red2[3][1];
  float m2 = zt1 * (1.f / 512.f);
  float v2 = zt2 * (1.f / 512.f) - m2 * m2;
  float sc2 = bn2_g[t] * rsqrtf(v2 + 1e-5f);
  float sh2 = bn2_b[t];
#pragma unroll
  for (int rr = 0; rr < 2; ++rr) {
    int b = tid * 2 + rr;
    float res = (z[rr] - m2) * sc2 + sh2;
    out[(size_t)b * 256 + t] = (res > 0.f) ? res : 0.f;
  }
}

extern "C" void kernel_launch(void* const* d_in, const int* in_sizes, int n_in,
                              void* d_out, int out_size, void* d_ws, size_t ws_size,
                              hipStream_t stream) {
  const float* x    = (const float*)d_in[0];
  const float* Wih  = (const float*)d_in[1];
  const float* Whh  = (const float*)d_in[2];
  const float* bih  = (const float*)d_in[3];
  const float* bhh  = (const float*)d_in[4];
  const float* fc1w = (const float*)d_in[5];
  const float* fc1b = (const float*)d_in[6];
  const float* fc2w = (const float*)d_in[7];
  const float* fc2b = (const float*)d_in[8];
  const float* b1g  = (const float*)d_in[9];
  const float* b1b  = (const float*)d_in[10];
  const float* b2g  = (const float*)d_in[11];
  const float* b2b  = (const float*)d_in[12];
  unsigned char* ws = (unsigned char*)d_ws;
  float* out = (float*)d_out;
  float* a_buf = (float*)(ws + OFF_XSWZ);   // reuses xswz region after persist

  zero_k<<<1028, 256, 0, stream>>>((unsigned*)ws, ZERO_WORDS);
  prep_x<<<8192, 256, 0, stream>>>(x, ws);
  lstm_persist<<<256, 512, 0, stream>>>(Wih, Whh, bih, bhh, ws);
  e1_fc1<<<1024, 256, 0, stream>>>(fc1w, ws + OFF_HIST, a_buf);
  e2_head<<<256, 256, 0, stream>>>(a_buf, fc1b, fc2w, fc2b, b1g, b1b, b2g, b2b, out);
}